// Round 5
// baseline (60.700 us; speedup 1.0000x reference)
//
#include <hip/hip_runtime.h>

typedef __attribute__((ext_vector_type(8)))  short bf16x8;
typedef __attribute__((ext_vector_type(16))) float f32x16;
typedef __attribute__((ext_vector_type(4)))  int   i32x4;

// pack 8 fp32 -> 8 bf16 (RNE) in fragment order: reg r holds elems {2r, 2r+1}
__device__ __forceinline__ unsigned cvt2(float lo, float hi) {
    unsigned r;
    asm volatile("v_cvt_pk_bf16_f32 %0, %1, %2" : "=v"(r) : "v"(lo), "v"(hi));
    return r;
}
__device__ __forceinline__ bf16x8 pack8(float4 a, float4 b) {
    union { i32x4 i; bf16x8 h; } c;
    c.i.x = cvt2(a.x, a.y);
    c.i.y = cvt2(a.z, a.w);
    c.i.z = cvt2(b.x, b.y);
    c.i.w = cvt2(b.z, b.w);
    return c.h;
}

// ---------------- init (atomic fallback only) ----------------
__global__ void caps_init(float* __restrict__ ws) {
    ws[blockIdx.x * 256 + threadIdx.x] = 0.0f;   // grid 256
}

// ---------------- main: MFMA bf16, distance-4 software pipeline ----------------
// grid 1024 = 64 j * 16 ic (128 i each), block 256 = 4 waves, 4 blocks/CU.
// wave w handles i = ibase + w + 4t, t = 0..31. One v_mfma_f32_32x32x16_bf16
// per step: A = x[32 b][16 d], B = W[j,i][16 d][32 c].
// A-frag: lane l reads x[b=l&31][i][d=(l>>5)*8 ..+7]   (32B, L2-resident)
// B-frag: lane l reads W[j][i][c=l&31][d=(l>>5)*8 ..+7] (32B, coalesced 2KB/wave)
// Pipeline: buffers s=0..3; step k consumes buf[s=k&3] issued at step k-4.
// No LDS / barriers in hot loop. Cross-wave C reduce once at the end.
template<int MODE>   // 0 = slab partials, 1 = atomicAdd
__global__ __launch_bounds__(256, 4)
void caps_mfma(const float* __restrict__ x, const float* __restrict__ W,
               float* __restrict__ ws)
{
    const int tid  = threadIdx.x;
    const int w    = tid >> 6;
    const int lane = tid & 63;
    const int m    = lane & 31;   // b for A / c for B
    const int h    = lane >> 5;   // k-half

    const int j     = blockIdx.x >> 4;
    const int ic    = blockIdx.x & 15;
    const int ibase = ic * 128;

    // byte addresses for step 0 (i = ibase + w); step k advances W by 8KB, x by 256B
    const char* Wb = (const char*)W + (((size_t)(j * 2048 + ibase + w)) << 11)
                   + (m << 6) + (h << 5);
    const char* Xb = (const char*)x + ((size_t)m << 17) + ((ibase + w) << 6) + (h << 5);

    f32x16 acc = {};

    float4 wv[4][2], xv[4][2];
    // prologue: issue steps 0..3
#pragma unroll
    for (int s = 0; s < 4; ++s) {
        wv[s][0] = *(const float4*)(Wb + s * 8192);
        wv[s][1] = *(const float4*)(Wb + s * 8192 + 16);
        xv[s][0] = *(const float4*)(Xb + s * 256);
        xv[s][1] = *(const float4*)(Xb + s * 256 + 16);
    }

    // main loop: steps t..t+3 consume, steps t+4..t+7 issue (t+7 <= 31)
#pragma unroll 1
    for (int t = 0; t < 28; t += 4) {
#pragma unroll
        for (int s = 0; s < 4; ++s) {
            bf16x8 afrag = pack8(xv[s][0], xv[s][1]);
            bf16x8 bfrag = pack8(wv[s][0], wv[s][1]);
            wv[s][0] = *(const float4*)(Wb + (s + 4) * 8192);
            wv[s][1] = *(const float4*)(Wb + (s + 4) * 8192 + 16);
            xv[s][0] = *(const float4*)(Xb + (s + 4) * 256);
            xv[s][1] = *(const float4*)(Xb + (s + 4) * 256 + 16);
            acc = __builtin_amdgcn_mfma_f32_32x32x16_bf16(afrag, bfrag, acc, 0, 0, 0);
        }
        Wb += 4 * 8192; Xb += 4 * 256;
    }
    // epilogue: consume steps 28..31
#pragma unroll
    for (int s = 0; s < 4; ++s)
        acc = __builtin_amdgcn_mfma_f32_32x32x16_bf16(
                  pack8(xv[s][0], xv[s][1]), pack8(wv[s][0], wv[s][1]), acc, 0, 0, 0);

    // ---- cross-wave reduce of C (b = (r&3)+8*(r>>2)+4*(lane>>5), c = lane&31) ----
    __shared__ float red[4096];   // [w][reg 0..15][lane 0..63]
#pragma unroll
    for (int r = 0; r < 16; ++r)
        red[w * 1024 + r * 64 + lane] = acc[r];
    __syncthreads();

#pragma unroll
    for (int e = 0; e < 4; ++e) {
        int idx = e * 256 + tid;             // b*32 + c
        int b = idx >> 5, c = idx & 31;
        int l = (((b >> 2) & 1) << 5) + c;
        int r = (b & 3) | (((b >> 3) & 3) << 2);
        float s = red[r * 64 + l] + red[1024 + r * 64 + l]
                + red[2048 + r * 64 + l] + red[3072 + r * 64 + l];
        if (MODE == 0)
            ws[(ic * 32 + b) * 2048 + j * 32 + c] = s;   // slab [ic][b][j*32+c]
        else
            atomicAdd(&ws[b * 2048 + j * 32 + c], s);
    }
}

// ---------------- finalize: sum chunks, scale 1/64, squash over c ----------------
template<int NIC>
__global__ void caps_finalize(const float* __restrict__ ws, float* __restrict__ out) {
    int o = blockIdx.x * 256 + threadIdx.x;   // b*2048 + j*32 + c ; grid 256
    int b = o >> 11;
    int rest = o & 2047;
    float v = 0.0f;
#pragma unroll
    for (int k = 0; k < NIC; ++k) v += ws[(k * 32 + b) * 2048 + rest];
    v *= (1.0f / 64.0f);
    float sq = v * v;
    sq += __shfl_xor(sq, 1, 64);
    sq += __shfl_xor(sq, 2, 64);
    sq += __shfl_xor(sq, 4, 64);
    sq += __shfl_xor(sq, 8, 64);
    sq += __shfl_xor(sq, 16, 64);
    float scale = sq / (1.0f + sq) / sqrtf(sq + 1e-7f);
    out[o] = scale * v;
}

// atomic-path finalize (ws already fully reduced)
__global__ void caps_finalize_a(const float* __restrict__ ws, float* __restrict__ out) {
    int o = blockIdx.x * 256 + threadIdx.x;
    float v = ws[o] * (1.0f / 64.0f);
    float sq = v * v;
    sq += __shfl_xor(sq, 1, 64);
    sq += __shfl_xor(sq, 2, 64);
    sq += __shfl_xor(sq, 4, 64);
    sq += __shfl_xor(sq, 8, 64);
    sq += __shfl_xor(sq, 16, 64);
    float scale = sq / (1.0f + sq) / sqrtf(sq + 1e-7f);
    out[o] = scale * v;
}

extern "C" void kernel_launch(void* const* d_in, const int* in_sizes, int n_in,
                              void* d_out, int out_size, void* d_ws, size_t ws_size,
                              hipStream_t stream) {
    (void)in_sizes; (void)n_in; (void)out_size;
    const float* x = (const float*)d_in[0];   // (32, 2048, 16) fp32
    const float* W = (const float*)d_in[1];   // (64, 2048, 32, 16) fp32
    float* out = (float*)d_out;               // (32, 64, 32) fp32
    float* ws  = (float*)d_ws;

    if (ws_size >= (size_t)16 * 65536 * sizeof(float)) {      // 4 MiB slab (proven)
        hipLaunchKernelGGL((caps_mfma<0>),     dim3(1024), dim3(256), 0, stream, x, W, ws);
        hipLaunchKernelGGL((caps_finalize<16>),dim3(256),  dim3(256), 0, stream, ws, out);
    } else {                                                  // atomic fallback
        float* acc_buf = (ws_size >= (size_t)65536 * sizeof(float)) ? ws : out;
        hipLaunchKernelGGL(caps_init,          dim3(256),  dim3(256), 0, stream, acc_buf);
        hipLaunchKernelGGL((caps_mfma<1>),     dim3(1024), dim3(256), 0, stream, x, W, acc_buf);
        hipLaunchKernelGGL(caps_finalize_a,    dim3(256),  dim3(256), 0, stream, acc_buf, out);
    }
}

// Round 6
// 52.867 us; speedup vs baseline: 1.1481x; 1.1481x over previous
//
#include <hip/hip_runtime.h>

typedef __attribute__((ext_vector_type(8)))  short bf16x8;
typedef __attribute__((ext_vector_type(16))) float f32x16;
typedef __attribute__((ext_vector_type(4)))  int   i32x4;

// pack 2 fp32 -> 2 bf16 (RNE)
__device__ __forceinline__ unsigned cvt2(float lo, float hi) {
    unsigned r;
    asm volatile("v_cvt_pk_bf16_f32 %0, %1, %2" : "=v"(r) : "v"(lo), "v"(hi));
    return r;
}
__device__ __forceinline__ bf16x8 pack8(float4 a, float4 b) {
    union { i32x4 i; bf16x8 h; } c;
    c.i.x = cvt2(a.x, a.y);
    c.i.y = cvt2(a.z, a.w);
    c.i.z = cvt2(b.x, b.y);
    c.i.w = cvt2(b.z, b.w);
    return c.h;
}

// ---------------- xconv: x (fp32, b-major) -> xf[i][lane] bf16 fragment order ----
// g = i*64 + l ; lane l holds x[b=l&31][i][d=(l>>5)*8 .. +7] as bf16x8 (16B).
__global__ void caps_xconv(const float* __restrict__ x, uint4* __restrict__ xf) {
    int g = blockIdx.x * 256 + threadIdx.x;   // grid 512 -> 131072 threads
    int i = g >> 6, l = g & 63;
    int b = l & 31, h = l >> 5;
    const float4* p = (const float4*)(x + (b * 2048 + i) * 16 + h * 8);
    float4 a = p[0], q = p[1];
    uint4 o;
    o.x = cvt2(a.x, a.y); o.y = cvt2(a.z, a.w);
    o.z = cvt2(q.x, q.y); o.w = cvt2(q.z, q.w);
    xf[g] = o;
}

// ---------------- init (atomic fallback only) ----------------
__global__ void caps_init(float* __restrict__ ws) {
    ws[blockIdx.x * 256 + threadIdx.x] = 0.0f;   // grid 256
}

// ---------------- main: MFMA bf16, distance-4 pipeline ----------------
// GATHER=0: A-frag = one coalesced bf16x8 load from xf. GATHER=1: inline fp32 gather.
// grid = 64 j * (2048/ICHUNK) ic ; block 256 = 4 waves; wave w: i = ibase + w + 4t.
template<int MODE, int GATHER, int ICHUNK>
__global__ __launch_bounds__(256, 4)
void caps_mfma(const float* __restrict__ x, const float* __restrict__ W,
               float* __restrict__ ws, const char* __restrict__ xf)
{
    constexpr int NIC = 2048 / ICHUNK;   // ic count
    constexpr int NT  = ICHUNK / 4;      // steps per wave

    const int tid  = threadIdx.x;
    const int w    = tid >> 6;
    const int lane = tid & 63;
    const int m    = lane & 31;   // b for A / c for B
    const int h    = lane >> 5;   // k-half

    const int j     = blockIdx.x / NIC;
    const int ic    = blockIdx.x % NIC;
    const int ibase = ic * ICHUNK;

    const char* Wb = (const char*)W + (((size_t)(j * 2048 + ibase + w)) << 11)
                   + (m << 6) + (h << 5);
    const char* Xb = (const char*)x + ((size_t)m << 17) + ((ibase + w) << 6) + (h << 5);
    const char* Xf = xf + ((ibase + w) << 10) + (lane << 4);

    f32x16 acc = {};

    float4 wv[4][2];
    bf16x8 xa[4];
    float4 xg[4][2];

#pragma unroll
    for (int s = 0; s < 4; ++s) {
        wv[s][0] = *(const float4*)(Wb + s * 8192);
        wv[s][1] = *(const float4*)(Wb + s * 8192 + 16);
        if (GATHER) {
            xg[s][0] = *(const float4*)(Xb + s * 256);
            xg[s][1] = *(const float4*)(Xb + s * 256 + 16);
        } else {
            xa[s] = *(const bf16x8*)(Xf + s * 4096);
        }
    }

#pragma unroll 1
    for (int t = 0; t < NT - 4; t += 4) {
#pragma unroll
        for (int s = 0; s < 4; ++s) {
            bf16x8 afrag = GATHER ? pack8(xg[s][0], xg[s][1]) : xa[s];
            bf16x8 bfrag = pack8(wv[s][0], wv[s][1]);
            wv[s][0] = *(const float4*)(Wb + (s + 4) * 8192);
            wv[s][1] = *(const float4*)(Wb + (s + 4) * 8192 + 16);
            if (GATHER) {
                xg[s][0] = *(const float4*)(Xb + (s + 4) * 256);
                xg[s][1] = *(const float4*)(Xb + (s + 4) * 256 + 16);
            } else {
                xa[s] = *(const bf16x8*)(Xf + (s + 4) * 4096);
            }
            acc = __builtin_amdgcn_mfma_f32_32x32x16_bf16(afrag, bfrag, acc, 0, 0, 0);
        }
        Wb += 4 * 8192; Xb += 4 * 256; Xf += 4 * 4096;
    }
#pragma unroll
    for (int s = 0; s < 4; ++s) {
        bf16x8 afrag = GATHER ? pack8(xg[s][0], xg[s][1]) : xa[s];
        acc = __builtin_amdgcn_mfma_f32_32x32x16_bf16(
                  afrag, pack8(wv[s][0], wv[s][1]), acc, 0, 0, 0);
    }

    // ---- cross-wave reduce of C (b = (r&3)+8*(r>>2)+4*(lane>>5), c = lane&31) ----
    __shared__ float red[4096];
#pragma unroll
    for (int r = 0; r < 16; ++r)
        red[w * 1024 + r * 64 + lane] = acc[r];
    __syncthreads();

#pragma unroll
    for (int e = 0; e < 4; ++e) {
        int idx = e * 256 + tid;             // b*32 + c
        int b = idx >> 5, c = idx & 31;
        int l = (((b >> 2) & 1) << 5) + c;
        int r = (b & 3) | (((b >> 3) & 3) << 2);
        float s = red[r * 64 + l] + red[1024 + r * 64 + l]
                + red[2048 + r * 64 + l] + red[3072 + r * 64 + l];
        if (MODE == 0)
            ws[(ic * 32 + b) * 2048 + j * 32 + c] = s;   // slab [ic][b][j*32+c]
        else
            atomicAdd(&ws[b * 2048 + j * 32 + c], s);
    }
}

// ---------------- finalize: sum chunks, scale 1/64, squash over c ----------------
template<int NIC>
__global__ void caps_finalize(const float* __restrict__ ws, float* __restrict__ out) {
    int o = blockIdx.x * 256 + threadIdx.x;   // b*2048 + j*32 + c ; grid 256
    int b = o >> 11;
    int rest = o & 2047;
    float v = 0.0f;
#pragma unroll
    for (int k = 0; k < NIC; ++k) v += ws[(k * 32 + b) * 2048 + rest];
    v *= (1.0f / 64.0f);
    float sq = v * v;
    sq += __shfl_xor(sq, 1, 64);
    sq += __shfl_xor(sq, 2, 64);
    sq += __shfl_xor(sq, 4, 64);
    sq += __shfl_xor(sq, 8, 64);
    sq += __shfl_xor(sq, 16, 64);
    float scale = sq / (1.0f + sq) / sqrtf(sq + 1e-7f);
    out[o] = scale * v;
}

__global__ void caps_finalize_a(const float* __restrict__ ws, float* __restrict__ out) {
    int o = blockIdx.x * 256 + threadIdx.x;
    float v = ws[o] * (1.0f / 64.0f);
    float sq = v * v;
    sq += __shfl_xor(sq, 1, 64);
    sq += __shfl_xor(sq, 2, 64);
    sq += __shfl_xor(sq, 4, 64);
    sq += __shfl_xor(sq, 8, 64);
    sq += __shfl_xor(sq, 16, 64);
    float scale = sq / (1.0f + sq) / sqrtf(sq + 1e-7f);
    out[o] = scale * v;
}

extern "C" void kernel_launch(void* const* d_in, const int* in_sizes, int n_in,
                              void* d_out, int out_size, void* d_ws, size_t ws_size,
                              hipStream_t stream) {
    (void)in_sizes; (void)n_in; (void)out_size;
    const float* x = (const float*)d_in[0];   // (32, 2048, 16) fp32
    const float* W = (const float*)d_in[1];   // (64, 2048, 32, 16) fp32
    float* out = (float*)d_out;               // (32, 64, 32) fp32
    float* ws  = (float*)d_ws;

    // layout: slab [32][32][2048] fp32 = 8 MiB, then xf 2 MiB
    const size_t slab_f = (size_t)32 * 32 * 2048;            // floats
    const size_t need   = slab_f * 4 + (size_t)2048 * 1024;  // 10 MiB

    if (ws_size >= need) {
        char* xf = (char*)(ws + slab_f);
        hipLaunchKernelGGL(caps_xconv,            dim3(512),  dim3(256), 0, stream, x, (uint4*)xf);
        hipLaunchKernelGGL((caps_mfma<0, 0, 64>), dim3(2048), dim3(256), 0, stream, x, W, ws, xf);
        hipLaunchKernelGGL((caps_finalize<32>),   dim3(256),  dim3(256), 0, stream, ws, out);
    } else if (ws_size >= (size_t)16 * 65536 * sizeof(float)) {   // 4 MiB slab (R4 path)
        hipLaunchKernelGGL((caps_mfma<0, 1, 128>), dim3(1024), dim3(256), 0, stream, x, W, ws, (const char*)0);
        // NOTE: slab path with ICHUNK=128 writes [ic<16][b][j*32+c]; reduce 16 chunks
        hipLaunchKernelGGL((caps_finalize<16>),    dim3(256),  dim3(256), 0, stream, ws, out);
    } else {
        float* acc_buf = (ws_size >= (size_t)65536 * sizeof(float)) ? ws : out;
        hipLaunchKernelGGL(caps_init,              dim3(256),  dim3(256), 0, stream, acc_buf);
        hipLaunchKernelGGL((caps_mfma<1, 1, 128>), dim3(1024), dim3(256), 0, stream, x, W, acc_buf, (const char*)0);
        hipLaunchKernelGGL(caps_finalize_a,        dim3(256),  dim3(256), 0, stream, acc_buf, out);
    }
}